// Round 1
// baseline (707.721 us; speedup 1.0000x reference)
//
#include <hip/hip_runtime.h>
#include <math.h>

#define D_INNER 128
#define L_SEQ 256

__device__ __forceinline__ float silu_f(float x) { return x / (1.f + __expf(-x)); }

__global__ __launch_bounds__(256, 2)
void mamba_fused(const float* __restrict__ reads,
                 const float* __restrict__ exp_w, const float* __restrict__ exp_b,
                 const float* __restrict__ in_proj_w,
                 const float* __restrict__ conv_w, const float* __restrict__ conv_b,
                 const float* __restrict__ x_proj_w,
                 const float* __restrict__ dt_w, const float* __restrict__ dt_b,
                 const float* __restrict__ A_log, const float* __restrict__ D_skip,
                 const float* __restrict__ out_proj_w,
                 float* __restrict__ pooled)
{
    const int b = blockIdx.x;
    const int t = threadIdx.x;

    __shared__ float xw_lds[D_INNER * 36];    // x_proj_w (128,36)
    __shared__ float wout_lds[D_INNER * 64];  // out_proj_w (128,64)
    __shared__ __align__(16) float x_lds[64];
    __shared__ float ring[4][D_INNER];        // last 4 xm vectors (conv history)
    __shared__ float zs_lds[D_INNER];         // silu(z)
    __shared__ float xc_lds[D_INNER];         // conv output after silu
    __shared__ float proj_lds[36];            // dt(4) | B(16) | C(16)
    __shared__ float g_lds[D_INNER];          // (y + xc*D) * silu(z)
    __shared__ float pacc[4][64];             // out_proj partials

    // in_proj column t in registers (the hot 64->256 GEMV)
    float w_in[64];
#pragma unroll
    for (int k = 0; k < 64; ++k) w_in[k] = in_proj_w[k * 256 + t];

    for (int i = t; i < D_INNER * 36; i += 256) xw_lds[i] = x_proj_w[i];
    for (int i = t; i < D_INNER * 64; i += 256) wout_lds[i] = out_proj_w[i];

    // per-channel (d = t < 128) parameters
    float convw[4] = {0,0,0,0}, dtw[4] = {0,0,0,0}, Avals[16], h[16];
    float convb = 0.f, dtb = 0.f, dskip = 0.f;
#pragma unroll
    for (int n = 0; n < 16; ++n) { Avals[n] = 0.f; h[n] = 0.f; }
    if (t < D_INNER) {
#pragma unroll
        for (int k = 0; k < 4; ++k) convw[k] = conv_w[t * 4 + k];
#pragma unroll
        for (int k = 0; k < 4; ++k) dtw[k] = dt_w[k * D_INNER + t];
        convb = conv_b[t]; dtb = dt_b[t]; dskip = D_skip[t];
#pragma unroll
        for (int n = 0; n < 16; ++n) Avals[n] = -__expf(A_log[t * 16 + n]);
        ring[0][t] = 0.f; ring[1][t] = 0.f; ring[2][t] = 0.f; ring[3][t] = 0.f;
    }

    float ew0 = 0, ew1 = 0, ew2 = 0, ew3 = 0, eb = 0;
    if (t < 64) {
        ew0 = exp_w[t]; ew1 = exp_w[64 + t]; ew2 = exp_w[128 + t]; ew3 = exp_w[192 + t];
        eb = exp_b[t];
    }

    float mean_acc = 0.f, last_val = 0.f;
    const int oc = t & 63, part = t >> 6;

    __syncthreads();

    const float4* rd_ptr = (const float4*)(reads) + (size_t)b * L_SEQ;

    for (int l = 0; l < L_SEQ; ++l) {
        // A: expansion reads(4) @ exp_w -> x(64)
        if (t < 64) {
            float4 r = rd_ptr[l];
            x_lds[t] = eb + r.x * ew0 + r.y * ew1 + r.z * ew2 + r.w * ew3;
        }
        __syncthreads();

        // B: in_proj x(64) @ (64,256); cols 0..127 = xm -> ring, 128..255 = z -> silu
        float acc = 0.f;
#pragma unroll
        for (int k = 0; k < 64; k += 4) {
            float4 xv = *(const float4*)&x_lds[k];
            acc += xv.x * w_in[k] + xv.y * w_in[k + 1] + xv.z * w_in[k + 2] + xv.w * w_in[k + 3];
        }
        if (t < D_INNER) ring[l & 3][t] = acc;
        else             zs_lds[t - D_INNER] = silu_f(acc);
        __syncthreads();

        // C: causal depthwise conv (k=4) + silu
        if (t < D_INNER) {
            float s = convb;
#pragma unroll
            for (int k = 0; k < 4; ++k) s += ring[(l + 1 + k) & 3][t] * convw[k];
            xc_lds[t] = silu_f(s);
        }
        __syncthreads();

        // D: x_proj xc(128) @ (128,36) -> dt|B|C ; 36 outputs x 4-lane groups
        if (t < 144) {
            int j = t >> 2, p = t & 3;
            float s = 0.f;
#pragma unroll
            for (int i = 0; i < 32; ++i) s += xc_lds[p * 32 + i] * xw_lds[(p * 32 + i) * 36 + j];
            s += __shfl_xor(s, 1);
            s += __shfl_xor(s, 2);
            if (p == 0) proj_lds[j] = s;
        }
        __syncthreads();

        // E: delta = softplus(dt @ dt_w + dt_b); selective-scan update; y = h.C
        if (t < D_INNER) {
            float dtr = dtb + proj_lds[0] * dtw[0] + proj_lds[1] * dtw[1]
                            + proj_lds[2] * dtw[2] + proj_lds[3] * dtw[3];
            float delta = fmaxf(dtr, 0.f) + log1pf(__expf(-fabsf(dtr)));
            float u = xc_lds[t];
            float du = delta * u;
            float y = 0.f;
#pragma unroll
            for (int n = 0; n < 16; ++n) {
                float e = __expf(delta * Avals[n]);
                h[n] = e * h[n] + du * proj_lds[4 + n];
                y = fmaf(h[n], proj_lds[20 + n], y);
            }
            g_lds[t] = (y + u * dskip) * zs_lds[t];
        }
        __syncthreads();

        // F: out_proj g(128) @ (128,64): wave `part` handles inner slice part*32..+32
        {
            float s = 0.f;
#pragma unroll
            for (int i = 0; i < 32; ++i) s += g_lds[part * 32 + i] * wout_lds[(part * 32 + i) * 64 + oc];
            pacc[part][oc] = s;
        }
        __syncthreads();

        // G: reduce partials; accumulate mean and keep last (enc never materialized)
        if (t < 64) {
            float tot = pacc[0][t] + pacc[1][t] + pacc[2][t] + pacc[3][t];
            mean_acc += tot;
            if (l == L_SEQ - 1) last_val = tot;
        }
        // no barrier needed: pacc next written after >=2 barriers
    }

    if (t < 64) {
        pooled[b * 128 + t] = mean_acc * (1.f / L_SEQ);
        pooled[b * 128 + 64 + t] = last_val;
    }
}

// keysT[oc][m] = pooled[m] @ k_w[:,oc] + k_b[oc], stored transposed for coalesced QK reads
__global__ __launch_bounds__(64)
void keys_kernel(const float* __restrict__ pooled,
                 const float* __restrict__ k_w, const float* __restrict__ k_b,
                 float* __restrict__ keysT, int B)
{
    int m = blockIdx.x, t = threadIdx.x;
    __shared__ float p_lds[128];
    p_lds[t] = pooled[m * 128 + t];
    p_lds[64 + t] = pooled[m * 128 + 64 + t];
    __syncthreads();
    float s = k_b[t];
#pragma unroll
    for (int i = 0; i < 128; ++i) s = fmaf(p_lds[i], k_w[i * 64 + t], s);
    keysT[t * B + m] = s;
}

// per query row: q = pooled[idx[n]] @ q_w + q_b; out[n,:] = q @ keysT
__global__ __launch_bounds__(256)
void qk_kernel(const float* __restrict__ pooled, const int* __restrict__ idx,
               const float* __restrict__ q_w, const float* __restrict__ q_b,
               const float* __restrict__ keysT, float* __restrict__ out, int B)
{
    int n = blockIdx.x, t = threadIdx.x;
    __shared__ float p_lds[128];
    __shared__ float q_lds[64];
    int bi = idx[n];
    if (t < 128) p_lds[t] = pooled[bi * 128 + t];
    __syncthreads();
    if (t < 64) {
        float s = q_b[t];
#pragma unroll
        for (int i = 0; i < 128; ++i) s = fmaf(p_lds[i], q_w[i * 64 + t], s);
        q_lds[t] = s;
    }
    __syncthreads();
    for (int m = t; m < B; m += 256) {
        float acc = 0.f;
#pragma unroll
        for (int i = 0; i < 64; ++i) acc = fmaf(q_lds[i], keysT[i * B + m], acc);
        out[(size_t)n * B + m] = acc;
    }
}

extern "C" void kernel_launch(void* const* d_in, const int* in_sizes, int n_in,
                              void* d_out, int out_size, void* d_ws, size_t ws_size,
                              hipStream_t stream)
{
    const float* reads      = (const float*)d_in[0];
    const int*   idx        = (const int*)d_in[1];
    const float* exp_w      = (const float*)d_in[2];
    const float* exp_b      = (const float*)d_in[3];
    const float* in_proj_w  = (const float*)d_in[4];
    const float* conv_w     = (const float*)d_in[5];
    const float* conv_b     = (const float*)d_in[6];
    const float* x_proj_w   = (const float*)d_in[7];
    const float* dt_w       = (const float*)d_in[8];
    const float* dt_b       = (const float*)d_in[9];
    const float* A_log      = (const float*)d_in[10];
    const float* D_skip     = (const float*)d_in[11];
    const float* out_proj_w = (const float*)d_in[12];
    const float* q_w        = (const float*)d_in[13];
    const float* q_b        = (const float*)d_in[14];
    const float* k_w        = (const float*)d_in[15];
    const float* k_b        = (const float*)d_in[16];

    const int B = in_sizes[0] / (L_SEQ * 4);
    const int N = in_sizes[1];

    float* pooled = (float*)d_ws;                  // B * 128
    float* keysT  = pooled + (size_t)B * 128;      // 64 * B

    mamba_fused<<<B, 256, 0, stream>>>(reads, exp_w, exp_b, in_proj_w, conv_w, conv_b,
                                       x_proj_w, dt_w, dt_b, A_log, D_skip, out_proj_w,
                                       pooled);
    keys_kernel<<<B, 64, 0, stream>>>(pooled, k_w, k_b, keysT, B);
    qk_kernel<<<N, 256, 0, stream>>>(pooled, idx, q_w, q_b, keysT, (float*)d_out, B);
}

// Round 2
// 479.015 us; speedup vs baseline: 1.4775x; 1.4775x over previous
//
#include <hip/hip_runtime.h>
#include <math.h>

typedef __attribute__((ext_vector_type(8))) _Float16 half8;

#define L_SEQ 256
#define D_INNER 128

__device__ __forceinline__ float silu_f(float x) { return x / (1.f + __expf(-x)); }
__device__ __forceinline__ float softplus_f(float x) {
    return fmaxf(x, 0.f) + log1pf(__expf(-fabsf(x)));
}

// ============================ FAST PATH ============================

// W_eff[j][c] = sum_k exp_w[j][k] * in_proj_w[k][c]; b_eff[c] = sum_k exp_b[k]*in_proj_w[k][c]
__global__ __launch_bounds__(256)
void k_weff(const float* __restrict__ exp_w, const float* __restrict__ exp_b,
            const float* __restrict__ in_proj_w, float* __restrict__ weff,
            float* __restrict__ beff)
{
    const int t = threadIdx.x;
    float a0 = 0, a1 = 0, a2 = 0, a3 = 0, ab = 0;
    for (int k = 0; k < 64; ++k) {
        float w = in_proj_w[k * 256 + t];
        a0 = fmaf(exp_w[k], w, a0);
        a1 = fmaf(exp_w[64 + k], w, a1);
        a2 = fmaf(exp_w[128 + k], w, a2);
        a3 = fmaf(exp_w[192 + k], w, a3);
        ab = fmaf(exp_b[k], w, ab);
    }
    weff[t] = a0; weff[256 + t] = a1; weff[512 + t] = a2; weff[768 + t] = a3;
    beff[t] = ab;
}

// Batch-parallel precompute of scan records: delta, xc, zs (fp16) and B|C (fp32).
// grid = B * 4 tiles of 64 steps; 256 threads.
__global__ __launch_bounds__(256, 2)
void precompute(const float* __restrict__ reads,
                const float* __restrict__ weff, const float* __restrict__ beff,
                const float* __restrict__ conv_w, const float* __restrict__ conv_b,
                const float* __restrict__ x_proj_w,
                const float* __restrict__ dt_w, const float* __restrict__ dt_b,
                _Float16* __restrict__ rdelta, _Float16* __restrict__ rxc,
                _Float16* __restrict__ rzs, float* __restrict__ rbc)
{
    const int b  = blockIdx.x >> 2;
    const int l0 = (blockIdx.x & 3) << 6;
    const int t  = threadIdx.x;

    __shared__ __align__(16) float     XM[67 * 128];   // xm with 3-step halo (fp32)
    __shared__ __align__(16) _Float16  XC[64 * 136];   // conv output (fp16, padded stride)
    __shared__ __align__(16) _Float16  XWT[36 * 136];  // x_proj_w transposed [j][k] (fp16)
    __shared__ float DT4[64 * 4];
    __shared__ __align__(16) float rA[67 * 4];

    for (int i = t; i < 128 * 36; i += 256) {
        int k = i / 36, j = i - k * 36;
        XWT[j * 136 + k] = (_Float16)x_proj_w[i];
    }
    for (int i = t; i < 67 * 4; i += 256) {
        int il = i >> 2, c = i & 3;
        int gl = l0 - 3 + il;
        rA[i] = (gl >= 0) ? reads[((size_t)b * L_SEQ + gl) * 4 + c] : 0.f;
    }
    __syncthreads();

    // xm = reads @ W_eff (+halo) -> XM ; z -> silu -> rzs (cols 128..255)
    {
        const float w0 = weff[t], w1 = weff[256 + t], w2 = weff[512 + t], w3 = weff[768 + t];
        const float be = beff[t];
        if (t < 128) {
            for (int i = 0; i < 67; ++i) {
                float4 rv = *(const float4*)&rA[i * 4];
                XM[i * 128 + t] = be + rv.x * w0 + rv.y * w1 + rv.z * w2 + rv.w * w3;
            }
        } else {
            const int c = t - 128;
            for (int i = 3; i < 67; ++i) {
                float4 rv = *(const float4*)&rA[i * 4];
                float v = be + rv.x * w0 + rv.y * w1 + rv.z * w2 + rv.w * w3;
                rzs[((size_t)b * L_SEQ + l0 + i - 3) * 128 + c] = (_Float16)silu_f(v);
            }
        }
    }
    __syncthreads();

    // causal depthwise conv + silu -> XC + rxc
    {
        const int d = t & 127;
        const float4 cw = ((const float4*)conv_w)[d];
        const float cb = conv_b[d];
        for (int l = t >> 7; l < 64; l += 2) {
            float s = cb + XM[l * 128 + d] * cw.x + XM[(l + 1) * 128 + d] * cw.y
                         + XM[(l + 2) * 128 + d] * cw.z + XM[(l + 3) * 128 + d] * cw.w;
            float xc = silu_f(s);
            XC[l * 136 + d] = (_Float16)xc;
            rxc[((size_t)b * L_SEQ + l0 + l) * 128 + d] = (_Float16)xc;
        }
    }
    __syncthreads();

    // x_proj: 2x2 register tiles over (l, j); j<4 -> DT4, else -> rbc
    for (int task = t; task < 576; task += 256) {
        const int lg = task / 18, jg = task - lg * 18;
        const int l = lg * 2, j = jg * 2;
        float a00 = 0, a01 = 0, a10 = 0, a11 = 0;
        const half8* xr0 = (const half8*)&XC[l * 136];
        const half8* xr1 = (const half8*)&XC[(l + 1) * 136];
        const half8* w0p = (const half8*)&XWT[j * 136];
        const half8* w1p = (const half8*)&XWT[(j + 1) * 136];
#pragma unroll
        for (int kq = 0; kq < 16; ++kq) {
            half8 x0 = xr0[kq], x1 = xr1[kq], wa = w0p[kq], wb = w1p[kq];
#pragma unroll
            for (int e = 0; e < 8; ++e) {
                float xf0 = (float)x0[e], xf1 = (float)x1[e];
                float wf0 = (float)wa[e], wf1 = (float)wb[e];
                a00 = fmaf(xf0, wf0, a00); a01 = fmaf(xf0, wf1, a01);
                a10 = fmaf(xf1, wf0, a10); a11 = fmaf(xf1, wf1, a11);
            }
        }
        const size_t row0 = (size_t)b * L_SEQ + l0 + l;
        if (j < 4)     DT4[l * 4 + j] = a00;       else rbc[row0 * 32 + (j - 4)] = a00;
        if (j + 1 < 4) DT4[l * 4 + j + 1] = a01;   else rbc[row0 * 32 + (j - 3)] = a01;
        if (j < 4)     DT4[(l + 1) * 4 + j] = a10; else rbc[(row0 + 1) * 32 + (j - 4)] = a10;
        if (j + 1 < 4) DT4[(l + 1) * 4 + j + 1] = a11; else rbc[(row0 + 1) * 32 + (j - 3)] = a11;
    }
    __syncthreads();

    // delta = softplus(dt @ dt_w + dt_b)
    {
        const int d = t & 127;
        const float dw0 = dt_w[d], dw1 = dt_w[128 + d], dw2 = dt_w[256 + d], dw3 = dt_w[384 + d];
        const float db = dt_b[d];
        for (int l = t >> 7; l < 64; l += 2) {
            float dtr = db + DT4[l * 4] * dw0 + DT4[l * 4 + 1] * dw1
                           + DT4[l * 4 + 2] * dw2 + DT4[l * 4 + 3] * dw3;
            rdelta[((size_t)b * L_SEQ + l0 + l) * 128 + d] = (_Float16)softplus_f(dtr);
        }
    }
}

// Barrier-free selective scan: one block per sequence, thread = channel.
// Accumulates sum(g) and g_last only (out_proj is linear), then one 128x64 GEMV.
__global__ __launch_bounds__(128)
void scan_kernel(const _Float16* __restrict__ rdelta, const _Float16* __restrict__ rxc,
                 const _Float16* __restrict__ rzs, const float* __restrict__ rbc,
                 const float* __restrict__ A_log, const float* __restrict__ D_skip,
                 const float* __restrict__ out_proj_w, float* __restrict__ pooled)
{
    const int b = blockIdx.x, d = threadIdx.x;
    __shared__ float gbuf[256];

    float Ak[16];
    bool structured = true;
#pragma unroll
    for (int n = 0; n < 16; ++n) {
        float a = -__expf(A_log[d * 16 + n]);
        structured = structured && (fabsf(a + (float)(n + 1)) < 1e-3f);
        Ak[n] = a * 1.44269504f;
    }
    const float dskip = D_skip[d];
    const size_t rowbase = (size_t)b * L_SEQ;
    const _Float16* pd = rdelta + rowbase * 128 + d;
    const _Float16* px = rxc + rowbase * 128 + d;
    const _Float16* pz = rzs + rowbase * 128 + d;
    const float4* pbc = (const float4*)(rbc + rowbase * 32);

    float h[16];
#pragma unroll
    for (int n = 0; n < 16; ++n) h[n] = 0.f;
    float gsum = 0.f, glast = 0.f;

    float deN = (float)pd[0], xcN = (float)px[0], zsN = (float)pz[0];
    for (int l = 0; l < L_SEQ; ++l) {
        const float de = deN, xc = xcN, zs = zsN;
        const int ln = (l + 1 < L_SEQ) ? l + 1 : l;
        deN = (float)pd[(size_t)ln * 128];
        xcN = (float)px[(size_t)ln * 128];
        zsN = (float)pz[(size_t)ln * 128];
        float4 B0 = pbc[l * 8 + 0], B1 = pbc[l * 8 + 1], B2 = pbc[l * 8 + 2], B3 = pbc[l * 8 + 3];
        float4 C0 = pbc[l * 8 + 4], C1 = pbc[l * 8 + 5], C2 = pbc[l * 8 + 6], C3 = pbc[l * 8 + 7];

        const float du = de * xc;
        float e[16];
        if (structured) {
            // A[n] == -(n+1): e[n] = r^(n+1), r = exp(-delta); log-depth product tree
            const float r = exp2f(de * -1.44269504f);
            const float r2 = r * r, r4 = r2 * r2, r8 = r4 * r4;
            const float r3 = r2 * r, r5 = r4 * r, r6 = r4 * r2, r7 = r4 * r3;
            e[0] = r;  e[1] = r2; e[2] = r3; e[3] = r4;
            e[4] = r5; e[5] = r6; e[6] = r7; e[7] = r8;
            e[8] = r8 * r;  e[9] = r8 * r2;  e[10] = r8 * r3;  e[11] = r8 * r4;
            e[12] = r8 * r5; e[13] = r8 * r6; e[14] = r8 * r7; e[15] = r8 * r8;
        } else {
#pragma unroll
            for (int n = 0; n < 16; ++n) e[n] = exp2f(de * Ak[n]);
        }
        const float Bv[16] = {B0.x, B0.y, B0.z, B0.w, B1.x, B1.y, B1.z, B1.w,
                              B2.x, B2.y, B2.z, B2.w, B3.x, B3.y, B3.z, B3.w};
        const float Cv[16] = {C0.x, C0.y, C0.z, C0.w, C1.x, C1.y, C1.z, C1.w,
                              C2.x, C2.y, C2.z, C2.w, C3.x, C3.y, C3.z, C3.w};
        float y = 0.f;
#pragma unroll
        for (int n = 0; n < 16; ++n) {
            h[n] = fmaf(e[n], h[n], du * Bv[n]);
            y = fmaf(h[n], Cv[n], y);
        }
        const float g = fmaf(xc, dskip, y) * zs;
        gsum += g;
        if (l == L_SEQ - 1) glast = g;
    }

    gbuf[d] = gsum * (1.f / L_SEQ);
    gbuf[128 + d] = glast;
    __syncthreads();
    {
        const int half = d >> 6, oc = d & 63;
        const float* gb = &gbuf[half * 128];
        float s = 0.f;
#pragma unroll 16
        for (int dd = 0; dd < 128; ++dd) s = fmaf(gb[dd], out_proj_w[dd * 64 + oc], s);
        pooled[b * 128 + half * 64 + oc] = s;
    }
}

// ======================= SHARED TAIL KERNELS =======================

__global__ __launch_bounds__(64)
void keys_kernel(const float* __restrict__ pooled,
                 const float* __restrict__ k_w, const float* __restrict__ k_b,
                 float* __restrict__ keysT, int B)
{
    int m = blockIdx.x, t = threadIdx.x;
    __shared__ float p_lds[128];
    p_lds[t] = pooled[m * 128 + t];
    p_lds[64 + t] = pooled[m * 128 + 64 + t];
    __syncthreads();
    float s = k_b[t];
#pragma unroll
    for (int i = 0; i < 128; ++i) s = fmaf(p_lds[i], k_w[i * 64 + t], s);
    keysT[t * B + m] = s;
}

__global__ __launch_bounds__(256)
void qk_kernel(const float* __restrict__ pooled, const int* __restrict__ idx,
               const float* __restrict__ q_w, const float* __restrict__ q_b,
               const float* __restrict__ keysT, float* __restrict__ out, int B)
{
    int n = blockIdx.x, t = threadIdx.x;
    __shared__ float p_lds[128];
    __shared__ float q_lds[64];
    int bi = idx[n];
    if (t < 128) p_lds[t] = pooled[bi * 128 + t];
    __syncthreads();
    if (t < 64) {
        float s = q_b[t];
#pragma unroll
        for (int i = 0; i < 128; ++i) s = fmaf(p_lds[i], q_w[i * 64 + t], s);
        q_lds[t] = s;
    }
    __syncthreads();
    for (int m = t; m < B; m += 256) {
        float acc = 0.f;
#pragma unroll
        for (int i = 0; i < 64; ++i) acc = fmaf(q_lds[i], keysT[i * B + m], acc);
        out[(size_t)n * B + m] = acc;
    }
}

// ===================== FALLBACK (round-1 fused) =====================

__global__ __launch_bounds__(256, 2)
void mamba_fused(const float* __restrict__ reads,
                 const float* __restrict__ exp_w, const float* __restrict__ exp_b,
                 const float* __restrict__ in_proj_w,
                 const float* __restrict__ conv_w, const float* __restrict__ conv_b,
                 const float* __restrict__ x_proj_w,
                 const float* __restrict__ dt_w, const float* __restrict__ dt_b,
                 const float* __restrict__ A_log, const float* __restrict__ D_skip,
                 const float* __restrict__ out_proj_w,
                 float* __restrict__ pooled)
{
    const int b = blockIdx.x;
    const int t = threadIdx.x;
    __shared__ float xw_lds[D_INNER * 36];
    __shared__ float wout_lds[D_INNER * 64];
    __shared__ __align__(16) float x_lds[64];
    __shared__ float ring[4][D_INNER];
    __shared__ float zs_lds[D_INNER];
    __shared__ float xc_lds[D_INNER];
    __shared__ float proj_lds[36];
    __shared__ float g_lds[D_INNER];
    __shared__ float pacc[4][64];

    float w_in[64];
#pragma unroll
    for (int k = 0; k < 64; ++k) w_in[k] = in_proj_w[k * 256 + t];
    for (int i = t; i < D_INNER * 36; i += 256) xw_lds[i] = x_proj_w[i];
    for (int i = t; i < D_INNER * 64; i += 256) wout_lds[i] = out_proj_w[i];

    float convw[4] = {0, 0, 0, 0}, dtw[4] = {0, 0, 0, 0}, Avals[16], h[16];
    float convb = 0.f, dtb = 0.f, dskip = 0.f;
#pragma unroll
    for (int n = 0; n < 16; ++n) { Avals[n] = 0.f; h[n] = 0.f; }
    if (t < D_INNER) {
#pragma unroll
        for (int k = 0; k < 4; ++k) convw[k] = conv_w[t * 4 + k];
#pragma unroll
        for (int k = 0; k < 4; ++k) dtw[k] = dt_w[k * D_INNER + t];
        convb = conv_b[t]; dtb = dt_b[t]; dskip = D_skip[t];
#pragma unroll
        for (int n = 0; n < 16; ++n) Avals[n] = -__expf(A_log[t * 16 + n]);
        ring[0][t] = 0.f; ring[1][t] = 0.f; ring[2][t] = 0.f; ring[3][t] = 0.f;
    }
    float ew0 = 0, ew1 = 0, ew2 = 0, ew3 = 0, eb = 0;
    if (t < 64) {
        ew0 = exp_w[t]; ew1 = exp_w[64 + t]; ew2 = exp_w[128 + t]; ew3 = exp_w[192 + t];
        eb = exp_b[t];
    }
    float mean_acc = 0.f, last_val = 0.f;
    const int oc = t & 63, part = t >> 6;
    __syncthreads();
    const float4* rd_ptr = (const float4*)(reads) + (size_t)b * L_SEQ;
    for (int l = 0; l < L_SEQ; ++l) {
        if (t < 64) {
            float4 r = rd_ptr[l];
            x_lds[t] = eb + r.x * ew0 + r.y * ew1 + r.z * ew2 + r.w * ew3;
        }
        __syncthreads();
        float acc = 0.f;
#pragma unroll
        for (int k = 0; k < 64; k += 4) {
            float4 xv = *(const float4*)&x_lds[k];
            acc += xv.x * w_in[k] + xv.y * w_in[k + 1] + xv.z * w_in[k + 2] + xv.w * w_in[k + 3];
        }
        if (t < D_INNER) ring[l & 3][t] = acc;
        else             zs_lds[t - D_INNER] = silu_f(acc);
        __syncthreads();
        if (t < D_INNER) {
            float s = convb;
#pragma unroll
            for (int k = 0; k < 4; ++k) s += ring[(l + 1 + k) & 3][t] * convw[k];
            xc_lds[t] = silu_f(s);
        }
        __syncthreads();
        if (t < 144) {
            int j = t >> 2, p = t & 3;
            float s = 0.f;
#pragma unroll
            for (int i = 0; i < 32; ++i) s += xc_lds[p * 32 + i] * xw_lds[(p * 32 + i) * 36 + j];
            s += __shfl_xor(s, 1);
            s += __shfl_xor(s, 2);
            if (p == 0) proj_lds[j] = s;
        }
        __syncthreads();
        if (t < D_INNER) {
            float dtr = dtb + proj_lds[0] * dtw[0] + proj_lds[1] * dtw[1]
                            + proj_lds[2] * dtw[2] + proj_lds[3] * dtw[3];
            float delta = fmaxf(dtr, 0.f) + log1pf(__expf(-fabsf(dtr)));
            float u = xc_lds[t];
            float du = delta * u;
            float y = 0.f;
#pragma unroll
            for (int n = 0; n < 16; ++n) {
                float e = __expf(delta * Avals[n]);
                h[n] = e * h[n] + du * proj_lds[4 + n];
                y = fmaf(h[n], proj_lds[20 + n], y);
            }
            g_lds[t] = (y + u * dskip) * zs_lds[t];
        }
        __syncthreads();
        {
            float s = 0.f;
#pragma unroll
            for (int i = 0; i < 32; ++i) s += g_lds[part * 32 + i] * wout_lds[(part * 32 + i) * 64 + oc];
            pacc[part][oc] = s;
        }
        __syncthreads();
        if (t < 64) {
            float tot = pacc[0][t] + pacc[1][t] + pacc[2][t] + pacc[3][t];
            mean_acc += tot;
            if (l == L_SEQ - 1) last_val = tot;
        }
    }
    if (t < 64) {
        pooled[b * 128 + t] = mean_acc * (1.f / L_SEQ);
        pooled[b * 128 + 64 + t] = last_val;
    }
}

// ============================ LAUNCH ============================

extern "C" void kernel_launch(void* const* d_in, const int* in_sizes, int n_in,
                              void* d_out, int out_size, void* d_ws, size_t ws_size,
                              hipStream_t stream)
{
    const float* reads      = (const float*)d_in[0];
    const int*   idx        = (const int*)d_in[1];
    const float* exp_w      = (const float*)d_in[2];
    const float* exp_b      = (const float*)d_in[3];
    const float* in_proj_w  = (const float*)d_in[4];
    const float* conv_w     = (const float*)d_in[5];
    const float* conv_b     = (const float*)d_in[6];
    const float* x_proj_w   = (const float*)d_in[7];
    const float* dt_w       = (const float*)d_in[8];
    const float* dt_b       = (const float*)d_in[9];
    const float* A_log      = (const float*)d_in[10];
    const float* D_skip     = (const float*)d_in[11];
    const float* out_proj_w = (const float*)d_in[12];
    const float* q_w        = (const float*)d_in[13];
    const float* q_b        = (const float*)d_in[14];
    const float* k_w        = (const float*)d_in[15];
    const float* k_b        = (const float*)d_in[16];

    const int B = in_sizes[0] / (L_SEQ * 4);
    const int N = in_sizes[1];
    const size_t ROWS = (size_t)B * L_SEQ;

    char* wsb = (char*)d_ws;
    float* pooled = (float*)(wsb);                         // B*128 f32
    float* keysT  = (float*)(wsb + 262144);                // 64*B f32
    float* weff   = (float*)(wsb + 393216);                // 4*256 f32
    float* beff   = (float*)(wsb + 397312);                // 256 f32

    const size_t off_delta = 1048576;
    const size_t sz_half   = ROWS * 128 * sizeof(_Float16);
    const size_t off_xc    = off_delta + sz_half;
    const size_t off_zs    = off_xc + sz_half;
    const size_t off_bc    = off_zs + sz_half;
    const size_t need      = off_bc + ROWS * 32 * sizeof(float);

    if (ws_size >= need) {
        _Float16* rdelta = (_Float16*)(wsb + off_delta);
        _Float16* rxc    = (_Float16*)(wsb + off_xc);
        _Float16* rzs    = (_Float16*)(wsb + off_zs);
        float*    rbc    = (float*)(wsb + off_bc);

        k_weff<<<1, 256, 0, stream>>>(exp_w, exp_b, in_proj_w, weff, beff);
        precompute<<<B * 4, 256, 0, stream>>>(reads, weff, beff, conv_w, conv_b,
                                              x_proj_w, dt_w, dt_b,
                                              rdelta, rxc, rzs, rbc);
        scan_kernel<<<B, 128, 0, stream>>>(rdelta, rxc, rzs, rbc, A_log, D_skip,
                                           out_proj_w, pooled);
    } else {
        mamba_fused<<<B, 256, 0, stream>>>(reads, exp_w, exp_b, in_proj_w, conv_w, conv_b,
                                           x_proj_w, dt_w, dt_b, A_log, D_skip, out_proj_w,
                                           pooled);
    }
    keys_kernel<<<B, 64, 0, stream>>>(pooled, k_w, k_b, keysT, B);
    qk_kernel<<<N, 256, 0, stream>>>(pooled, idx, q_w, q_b, keysT, (float*)d_out, B);
}

// Round 3
// 240.581 us; speedup vs baseline: 2.9417x; 1.9911x over previous
//
#include <hip/hip_runtime.h>
#include <math.h>

typedef __attribute__((ext_vector_type(8))) _Float16 half8;

#define L_SEQ 256
#define TILE 32
#define NTILE 8

__device__ __forceinline__ float silu_f(float x) { return x / (1.f + __expf(-x)); }
__device__ __forceinline__ float softplus_f(float x) {
    return fmaxf(x, 0.f) + log1pf(__expf(-fabsf(x)));
}

// Fully fused Mamba encoder: one block per sequence, 8 tiles x 32 steps.
// All intermediates live in LDS; only `pooled` (B x 128) is written to HBM.
__global__ __launch_bounds__(256, 3)
void mamba_v3(const float* __restrict__ reads,
              const float* __restrict__ exp_w, const float* __restrict__ exp_b,
              const float* __restrict__ in_proj_w,
              const float* __restrict__ conv_w, const float* __restrict__ conv_b,
              const float* __restrict__ x_proj_w,
              const float* __restrict__ dt_w, const float* __restrict__ dt_b,
              const float* __restrict__ A_log, const float* __restrict__ D_skip,
              const float* __restrict__ out_proj_w,
              float* __restrict__ pooled)
{
    const int b = blockIdx.x, t = threadIdx.x;
    const int d = t & 127;           // channel owned by this thread
    const int lh = t >> 7;           // which 16-step half of the tile
    const int lbase = lh * 16;

    __shared__ __align__(16) float    RD[36 * 4];      // reads rows l0-3..l0+31
    __shared__ __align__(16) float    XCf[TILE * 132]; // conv out, f32, padded
    __shared__ __align__(16) _Float16 WPK[18 * 264];   // x_proj_w, j-pair interleaved
    __shared__ _Float16 ZS[TILE * 128];                // silu(z)
    __shared__ _Float16 DE[TILE * 128];                // delta
    __shared__ __align__(16) float    BC[TILE * 32];   // B(16) | C(16) per step
    __shared__ __align__(16) float    DT4[TILE * 4];   // dt-rank outputs

    // ---- prologue: fold exp_w @ in_proj_w into per-thread effective weights ----
    float wx0 = 0, wx1 = 0, wx2 = 0, wx3 = 0;   // xm column d
    float wz0 = 0, wz1 = 0, wz2 = 0, wz3 = 0;   // z column 128+d
    float bx = 0, bz = 0;
    for (int k = 0; k < 64; ++k) {
        float e0 = exp_w[k], e1 = exp_w[64 + k], e2 = exp_w[128 + k], e3 = exp_w[192 + k];
        float ebk = exp_b[k];
        float wa = in_proj_w[k * 256 + d];
        float wb = in_proj_w[k * 256 + 128 + d];
        wx0 = fmaf(e0, wa, wx0); wx1 = fmaf(e1, wa, wx1);
        wx2 = fmaf(e2, wa, wx2); wx3 = fmaf(e3, wa, wx3);
        wz0 = fmaf(e0, wb, wz0); wz1 = fmaf(e1, wb, wz1);
        wz2 = fmaf(e2, wb, wz2); wz3 = fmaf(e3, wb, wz3);
        bx = fmaf(ebk, wa, bx);  bz = fmaf(ebk, wb, bz);
    }

    const float4 cw = ((const float4*)conv_w)[d];
    const float cb = conv_b[d];
    const float dw0 = dt_w[d], dw1 = dt_w[128 + d], dw2 = dt_w[256 + d], dw3 = dt_w[384 + d];
    const float db = dt_b[d];

    float Ak[16], h[16];
    bool structured = true;
    float dskip = 0.f;
#pragma unroll
    for (int n = 0; n < 16; ++n) { h[n] = 0.f; Ak[n] = 0.f; }
    if (t < 128) {
#pragma unroll
        for (int n = 0; n < 16; ++n) {
            float a = -__expf(A_log[t * 16 + n]);
            structured = structured && (fabsf(a + (float)(n + 1)) < 1e-3f);
            Ak[n] = a * 1.44269504f;
        }
        dskip = D_skip[t];
    }

    // x_proj_w -> WPK: row jg holds (W[k][2jg], W[k][2jg+1]) pairs, stride 264 halfs
    for (int i = t; i < 128 * 36; i += 256) {
        int k = i / 36, j = i - k * 36;
        WPK[(j >> 1) * 264 + k * 2 + (j & 1)] = (_Float16)x_proj_w[i];
    }
    // reads rows for tile 0 (with 3-row causal halo)
    const float4* rdv = (const float4*)(reads + (size_t)b * L_SEQ * 4);
    if (t < 35) {
        int row = t - 3;
        float4 v = make_float4(0.f, 0.f, 0.f, 0.f);
        if (row >= 0) v = rdv[row];
        ((float4*)RD)[t] = v;
    }
    __syncthreads();

    float gsum = 0.f, glast = 0.f;

    for (int tile = 0; tile < NTILE; ++tile) {
        const int l0 = tile * TILE;

        // ---- Phase A+B: xm in registers (halo recomputed), z->ZS, conv->XCf ----
        float xm[19];
#pragma unroll
        for (int j = 0; j < 19; ++j) {
            int lm = lbase - 3 + j;   // tile-local step index of this xm
            float4 rv = ((const float4*)RD)[lm + 3];
            float v = bx + rv.x * wx0 + rv.y * wx1 + rv.z * wx2 + rv.w * wx3;
            xm[j] = (l0 + lm >= 0) ? v : 0.f;   // conv zero-pads xm before l=0
        }
#pragma unroll
        for (int i = 0; i < 16; ++i) {
            float4 rv = ((const float4*)RD)[lbase + i + 3];
            float z = bz + rv.x * wz0 + rv.y * wz1 + rv.z * wz2 + rv.w * wz3;
            ZS[(lbase + i) * 128 + d] = (_Float16)silu_f(z);
            float s = cb + xm[i] * cw.x + xm[i + 1] * cw.y + xm[i + 2] * cw.z + xm[i + 3] * cw.w;
            XCf[(lbase + i) * 132 + d] = silu_f(s);
        }
        __syncthreads();

        // ---- Phase C: x_proj (32 x 36 = [dt|B|C]) as 288 2x2-tile tasks ----
        if (t < 35 && tile + 1 < NTILE) {   // prefetch next tile's reads rows
            int row = (tile + 1) * TILE - 3 + t;
            ((float4*)RD)[t] = rdv[row];
        }
        for (int task = t; task < 288; task += 256) {
            const int lg = task / 18, jg = task - lg * 18;
            const float4* xr0 = (const float4*)&XCf[(2 * lg) * 132];
            const float4* xr1 = (const float4*)&XCf[(2 * lg + 1) * 132];
            const half8*  wp  = (const half8*)&WPK[jg * 264];
            float a00 = 0, a01 = 0, a10 = 0, a11 = 0;
#pragma unroll 8
            for (int kq = 0; kq < 32; ++kq) {   // 4 k per iteration
                half8 w = wp[kq];
                float4 xa = xr0[kq], xb = xr1[kq];
                float w00 = (float)w[0], w01 = (float)w[1];
                float w10 = (float)w[2], w11 = (float)w[3];
                float w20 = (float)w[4], w21 = (float)w[5];
                float w30 = (float)w[6], w31 = (float)w[7];
                a00 = fmaf(xa.x, w00, a00); a01 = fmaf(xa.x, w01, a01);
                a10 = fmaf(xb.x, w00, a10); a11 = fmaf(xb.x, w01, a11);
                a00 = fmaf(xa.y, w10, a00); a01 = fmaf(xa.y, w11, a01);
                a10 = fmaf(xb.y, w10, a10); a11 = fmaf(xb.y, w11, a11);
                a00 = fmaf(xa.z, w20, a00); a01 = fmaf(xa.z, w21, a01);
                a10 = fmaf(xb.z, w20, a10); a11 = fmaf(xb.z, w21, a11);
                a00 = fmaf(xa.w, w30, a00); a01 = fmaf(xa.w, w31, a01);
                a10 = fmaf(xb.w, w30, a10); a11 = fmaf(xb.w, w31, a11);
            }
            const int l = 2 * lg, j = 2 * jg;
            if (j < 4) {
                DT4[l * 4 + j] = a00;       DT4[l * 4 + j + 1] = a01;
                DT4[(l + 1) * 4 + j] = a10; DT4[(l + 1) * 4 + j + 1] = a11;
            } else {
                BC[l * 32 + j - 4] = a00;       BC[l * 32 + j - 3] = a01;
                BC[(l + 1) * 32 + j - 4] = a10; BC[(l + 1) * 32 + j - 3] = a11;
            }
        }
        __syncthreads();

        // ---- Phase D: delta = softplus(dt @ dt_w + dt_b) ----
#pragma unroll
        for (int i = 0; i < 16; ++i) {
            int l = lbase + i;
            float4 dv = ((const float4*)DT4)[l];
            float dtr = db + dv.x * dw0 + dv.y * dw1 + dv.z * dw2 + dv.w * dw3;
            DE[l * 128 + d] = (_Float16)softplus_f(dtr);
        }
        __syncthreads();

        // ---- Phase E: serial selective scan over the tile (threads = channels) ----
        if (t < 128) {
            for (int l = 0; l < TILE; ++l) {
                float de = (float)DE[l * 128 + t];
                float xc = XCf[l * 132 + t];
                float zs = (float)ZS[l * 128 + t];
                const float4* bcp = (const float4*)&BC[l * 32];
                float4 B0 = bcp[0], B1 = bcp[1], B2 = bcp[2], B3 = bcp[3];
                float4 C0 = bcp[4], C1 = bcp[5], C2 = bcp[6], C3 = bcp[7];
                const float du = de * xc;
                float e[16];
                if (structured) {
                    // A[n] == -(n+1): e[n] = r^(n+1), r = exp(-delta)
                    const float r = exp2f(de * -1.44269504f);
                    const float r2 = r * r, r4 = r2 * r2, r8 = r4 * r4;
                    const float r3 = r2 * r, r5 = r4 * r, r6 = r4 * r2, r7 = r4 * r3;
                    e[0] = r;  e[1] = r2; e[2] = r3; e[3] = r4;
                    e[4] = r5; e[5] = r6; e[6] = r7; e[7] = r8;
                    e[8] = r8 * r;   e[9] = r8 * r2;  e[10] = r8 * r3;  e[11] = r8 * r4;
                    e[12] = r8 * r5; e[13] = r8 * r6; e[14] = r8 * r7;  e[15] = r8 * r8;
                } else {
#pragma unroll
                    for (int n = 0; n < 16; ++n) e[n] = exp2f(de * Ak[n]);
                }
                const float Bv[16] = {B0.x, B0.y, B0.z, B0.w, B1.x, B1.y, B1.z, B1.w,
                                      B2.x, B2.y, B2.z, B2.w, B3.x, B3.y, B3.z, B3.w};
                const float Cv[16] = {C0.x, C0.y, C0.z, C0.w, C1.x, C1.y, C1.z, C1.w,
                                      C2.x, C2.y, C2.z, C2.w, C3.x, C3.y, C3.z, C3.w};
                float y = 0.f;
#pragma unroll
                for (int n = 0; n < 16; ++n) {
                    h[n] = fmaf(e[n], h[n], du * Bv[n]);
                    y = fmaf(h[n], Cv[n], y);
                }
                float g = fmaf(xc, dskip, y) * zs;
                gsum += g;
                glast = g;                       // ends as g at l = 255
            }
        }
        __syncthreads();
    }

    // ---- epilogue: pooled = [mean(g) @ W_out | g_last @ W_out] ----
    if (t < 128) { BC[t] = gsum * (1.f / L_SEQ); BC[128 + t] = glast; }
    __syncthreads();
    if (t < 128) {
        const int half = t >> 6, oc = t & 63;
        const float* gb = &BC[half * 128];
        float s = 0.f;
#pragma unroll 16
        for (int dd = 0; dd < 128; ++dd) s = fmaf(gb[dd], out_proj_w[dd * 64 + oc], s);
        pooled[b * 128 + t] = s;
    }
}

// ======================= TAIL KERNELS =======================

__global__ __launch_bounds__(64)
void keys_kernel(const float* __restrict__ pooled,
                 const float* __restrict__ k_w, const float* __restrict__ k_b,
                 float* __restrict__ keysT, int B)
{
    int m = blockIdx.x, t = threadIdx.x;
    __shared__ float p_lds[128];
    p_lds[t] = pooled[m * 128 + t];
    p_lds[64 + t] = pooled[m * 128 + 64 + t];
    __syncthreads();
    float s = k_b[t];
#pragma unroll
    for (int i = 0; i < 128; ++i) s = fmaf(p_lds[i], k_w[i * 64 + t], s);
    keysT[t * B + m] = s;
}

__global__ __launch_bounds__(256)
void qk_kernel(const float* __restrict__ pooled, const int* __restrict__ idx,
               const float* __restrict__ q_w, const float* __restrict__ q_b,
               const float* __restrict__ keysT, float* __restrict__ out, int B)
{
    int n = blockIdx.x, t = threadIdx.x;
    __shared__ float p_lds[128];
    __shared__ float q_lds[64];
    int bi = idx[n];
    if (t < 128) p_lds[t] = pooled[bi * 128 + t];
    __syncthreads();
    if (t < 64) {
        float s = q_b[t];
#pragma unroll
        for (int i = 0; i < 128; ++i) s = fmaf(p_lds[i], q_w[i * 64 + t], s);
        q_lds[t] = s;
    }
    __syncthreads();
    for (int m = t; m < B; m += 256) {
        float acc = 0.f;
#pragma unroll
        for (int i = 0; i < 64; ++i) acc = fmaf(q_lds[i], keysT[i * B + m], acc);
        out[(size_t)n * B + m] = acc;
    }
}

// ============================ LAUNCH ============================

extern "C" void kernel_launch(void* const* d_in, const int* in_sizes, int n_in,
                              void* d_out, int out_size, void* d_ws, size_t ws_size,
                              hipStream_t stream)
{
    const float* reads      = (const float*)d_in[0];
    const int*   idx        = (const int*)d_in[1];
    const float* exp_w      = (const float*)d_in[2];
    const float* exp_b      = (const float*)d_in[3];
    const float* in_proj_w  = (const float*)d_in[4];
    const float* conv_w     = (const float*)d_in[5];
    const float* conv_b     = (const float*)d_in[6];
    const float* x_proj_w   = (const float*)d_in[7];
    const float* dt_w       = (const float*)d_in[8];
    const float* dt_b       = (const float*)d_in[9];
    const float* A_log      = (const float*)d_in[10];
    const float* D_skip     = (const float*)d_in[11];
    const float* out_proj_w = (const float*)d_in[12];
    const float* q_w        = (const float*)d_in[13];
    const float* q_b        = (const float*)d_in[14];
    const float* k_w        = (const float*)d_in[15];
    const float* k_b        = (const float*)d_in[16];

    const int B = in_sizes[0] / (L_SEQ * 4);
    const int N = in_sizes[1];

    char* wsb = (char*)d_ws;
    float* pooled = (float*)(wsb);                    // B*128 f32
    float* keysT  = (float*)(wsb + (size_t)B * 128 * 4);

    mamba_v3<<<B, 256, 0, stream>>>(reads, exp_w, exp_b, in_proj_w, conv_w, conv_b,
                                    x_proj_w, dt_w, dt_b, A_log, D_skip, out_proj_w,
                                    pooled);
    keys_kernel<<<B, 64, 0, stream>>>(pooled, k_w, k_b, keysT, B);
    qk_kernel<<<N, 256, 0, stream>>>(pooled, idx, q_w, q_b, keysT, (float*)d_out, B);
}

// Round 4
// 224.912 us; speedup vs baseline: 3.1467x; 1.0697x over previous
//
#include <hip/hip_runtime.h>
#include <math.h>

#define L_SEQ 256
#define TILE 32

__device__ __forceinline__ float silu_f(float x) { return x / (1.f + __expf(-x)); }
// softplus via hw exp2/log2; accurate for |x| < 80
__device__ __forceinline__ float sp2_f(float x) {
    return log2f(1.f + exp2f(x * 1.44269504f)) * 0.69314718f;
}

// ---- prep: fold exp_w@in_proj_w -> weff/beff ; transpose x_proj_w -> [36][132] f32 ----
__global__ __launch_bounds__(256)
void k_prep(const float* __restrict__ exp_w, const float* __restrict__ exp_b,
            const float* __restrict__ in_proj_w, const float* __restrict__ x_proj_w,
            float* __restrict__ weff, float* __restrict__ beff, float* __restrict__ xpwt)
{
    const int t = threadIdx.x;
    float a0 = 0, a1 = 0, a2 = 0, a3 = 0, ab = 0;
    for (int k = 0; k < 64; ++k) {
        float w = in_proj_w[k * 256 + t];
        a0 = fmaf(exp_w[k], w, a0);
        a1 = fmaf(exp_w[64 + k], w, a1);
        a2 = fmaf(exp_w[128 + k], w, a2);
        a3 = fmaf(exp_w[192 + k], w, a3);
        ab = fmaf(exp_b[k], w, ab);
    }
    weff[t] = a0; weff[256 + t] = a1; weff[512 + t] = a2; weff[768 + t] = a3;
    beff[t] = ab;
    for (int i = t; i < 128 * 36; i += 256) {
        int k = i / 36, j = i - k * 36;
        xpwt[j * 132 + k] = x_proj_w[i];
    }
}

// ---- segmented fused Mamba: grid = B * nseg, one 64-step segment per block ----
__global__ __launch_bounds__(256, 4)
void mamba_seg(const float* __restrict__ reads,
               const float* __restrict__ weff, const float* __restrict__ beff,
               const float* __restrict__ xpwt,
               const float* __restrict__ conv_w, const float* __restrict__ conv_b,
               const float* __restrict__ dt_w, const float* __restrict__ dt_b,
               const float* __restrict__ A_log, const float* __restrict__ D_skip,
               float* __restrict__ Qg, float* __restrict__ Pg, float* __restrict__ Kg,
               float* __restrict__ GS, float* __restrict__ CZ, float* __restrict__ SL,
               int Bn, int seg_shift)
{
    const int nseg = 1 << seg_shift;
    const int ntile = (L_SEQ / TILE) >> seg_shift;
    const int bx = blockIdx.x;
    const int b = bx >> seg_shift;
    const int sidx = bx & (nseg - 1);
    const int seg0 = sidx * ntile * TILE;
    const int t = threadIdx.x;
    const int dA = t & 127, lh = t >> 7;   // phase A mapping (channel, l-half)
    const int dd = t >> 1,  g  = t & 1;    // phase E mapping (channel, n-group)

    __shared__ __align__(16) float RD[2][36 * 4];     // reads rows (+3 halo), dbuf
    __shared__ __align__(16) float XCf[TILE * 132];   // conv output, f32, padded
    __shared__ __align__(16) float BC[TILE * 32];     // B(16)|C(16) per step
    __shared__ __align__(16) float DT4[TILE * 4];     // dt-rank outputs

    // phase A weights (xm column dA)
    const float wx0 = weff[dA], wx1 = weff[256 + dA], wx2 = weff[512 + dA], wx3 = weff[768 + dA];
    const float bxc = beff[dA];
    const float4 cw = ((const float4*)conv_w)[dA];
    const float cb = conv_b[dA];
    // phase E per-lane weights: even lane -> z (silu), odd lane -> dt (softplus)
    float q0, q1, q2, q3, qb;
    if (g == 0) {
        q0 = weff[128 + dd]; q1 = weff[384 + dd]; q2 = weff[640 + dd]; q3 = weff[896 + dd];
        qb = beff[128 + dd];
    } else {
        q0 = dt_w[dd]; q1 = dt_w[128 + dd]; q2 = dt_w[256 + dd]; q3 = dt_w[384 + dd];
        qb = dt_b[dd];
    }
    const float dskip = D_skip[dd];
    bool structured = true;
#pragma unroll
    for (int k = 0; k < 8; ++k) {
        float a = -__expf(A_log[dd * 16 + g * 8 + k]);
        structured = structured && (fabsf(a + (float)(g * 8 + k + 1)) < 1e-3f);
    }

    const float4* rdv = (const float4*)(reads + (size_t)b * L_SEQ * 4);
    if (t < 35) {
        int row = seg0 - 3 + t;
        float4 v = make_float4(0.f, 0.f, 0.f, 0.f);
        if (row >= 0) v = rdv[row];
        ((float4*)RD[0])[t] = v;
    }

    float h[8], P[8], K[8], czs[8];
    float gsum = 0.f, sl = 0.f;
#pragma unroll
    for (int k = 0; k < 8; ++k) { h[k] = 0.f; P[k] = 1.f; K[k] = 0.f; czs[k] = 0.f; }

    __syncthreads();

    for (int tile = 0; tile < ntile; ++tile) {
        const int cur = tile & 1;
        const int l_off = seg0 + tile * TILE;
        const float4* RDc = (const float4*)RD[cur];

        // ---- phase A: xm (rolling window) + causal conv + silu -> XCf ----
        {
            const int lb = lh * 16;
            float x0, x1, x2;
            {
                float4 rv = RDc[lb + 0];
                x0 = bxc + rv.x * wx0 + rv.y * wx1 + rv.z * wx2 + rv.w * wx3;
                if (l_off + lb - 3 < 0) x0 = 0.f;
                rv = RDc[lb + 1];
                x1 = bxc + rv.x * wx0 + rv.y * wx1 + rv.z * wx2 + rv.w * wx3;
                if (l_off + lb - 2 < 0) x1 = 0.f;
                rv = RDc[lb + 2];
                x2 = bxc + rv.x * wx0 + rv.y * wx1 + rv.z * wx2 + rv.w * wx3;
                if (l_off + lb - 1 < 0) x2 = 0.f;
            }
#pragma unroll
            for (int i = 0; i < 16; ++i) {
                float4 rv = RDc[lb + 3 + i];
                float xn = bxc + rv.x * wx0 + rv.y * wx1 + rv.z * wx2 + rv.w * wx3;
                float s = cb + x0 * cw.x + x1 * cw.y + x2 * cw.z + xn * cw.w;
                XCf[(lb + i) * 132 + dA] = silu_f(s);
                x0 = x1; x1 = x2; x2 = xn;
            }
        }
        __syncthreads();

        // ---- phase C: x_proj (32 x 36) -> DT4|BC ; prefetch next RD ----
        if (t < 35 && tile + 1 < ntile) {
            int row = l_off + TILE - 3 + t;
            ((float4*)RD[cur ^ 1])[t] = rdv[row];
        }
        for (int task = t; task < 288; task += 256) {
            const int lg = task / 18, jg = task - lg * 18;
            const float4* xr0 = (const float4*)&XCf[(2 * lg) * 132];
            const float4* xr1 = (const float4*)&XCf[(2 * lg + 1) * 132];
            const float4* w0p = (const float4*)&xpwt[(2 * jg) * 132];
            const float4* w1p = (const float4*)&xpwt[(2 * jg + 1) * 132];
            float a00 = 0, a01 = 0, a10 = 0, a11 = 0;
#pragma unroll 8
            for (int kq = 0; kq < 32; ++kq) {
                float4 xa = xr0[kq], xb = xr1[kq];
                float4 wa = w0p[kq], wb = w1p[kq];
                a00 = fmaf(xa.x, wa.x, a00); a01 = fmaf(xa.x, wb.x, a01);
                a10 = fmaf(xb.x, wa.x, a10); a11 = fmaf(xb.x, wb.x, a11);
                a00 = fmaf(xa.y, wa.y, a00); a01 = fmaf(xa.y, wb.y, a01);
                a10 = fmaf(xb.y, wa.y, a10); a11 = fmaf(xb.y, wb.y, a11);
                a00 = fmaf(xa.z, wa.z, a00); a01 = fmaf(xa.z, wb.z, a01);
                a10 = fmaf(xb.z, wa.z, a10); a11 = fmaf(xb.z, wb.z, a11);
                a00 = fmaf(xa.w, wa.w, a00); a01 = fmaf(xa.w, wb.w, a01);
                a10 = fmaf(xb.w, wa.w, a10); a11 = fmaf(xb.w, wb.w, a11);
            }
            const int l = 2 * lg, j = 2 * jg;
            if (j < 4) {
                DT4[l * 4 + j] = a00;       DT4[l * 4 + j + 1] = a01;
                DT4[(l + 1) * 4 + j] = a10; DT4[(l + 1) * 4 + j + 1] = a11;
            } else {
                BC[l * 32 + j - 4] = a00;       BC[l * 32 + j - 3] = a01;
                BC[(l + 1) * 32 + j - 4] = a10; BC[(l + 1) * 32 + j - 3] = a11;
            }
        }
        __syncthreads();

        // ---- phase E: scan; 2 lanes per channel (n-split), zs/delta recomputed ----
        {
            const bool last_tile = (tile == ntile - 1);
            for (int l = 0; l < TILE; ++l) {
                float mine;
                if (g == 0) {
                    float4 rv = RDc[l + 3];
                    mine = silu_f(qb + rv.x * q0 + rv.y * q1 + rv.z * q2 + rv.w * q3);
                } else {
                    float4 dv = *(const float4*)&DT4[l * 4];
                    mine = sp2_f(qb + dv.x * q0 + dv.y * q1 + dv.z * q2 + dv.w * q3);
                }
                const float other = __shfl_xor(mine, 1);
                const float zs = g ? other : mine;
                const float de = g ? mine : other;
                const float xc = XCf[l * 132 + dd];
                const float du = de * xc;
                float e[8];
                if (structured) {       // A[n] = -(n+1): e[k] = r^(g*8+k+1)
                    const float r = exp2f(de * -1.44269504f);
                    const float p2 = r * r, p3 = p2 * r, p4 = p2 * p2;
                    const float p5 = p4 * r, p6 = p4 * p2, p7 = p4 * p3, p8 = p4 * p4;
                    const float base = g ? p8 : 1.0f;
                    e[0] = r * base;  e[1] = p2 * base; e[2] = p3 * base; e[3] = p4 * base;
                    e[4] = p5 * base; e[5] = p6 * base; e[6] = p7 * base; e[7] = p8 * base;
                } else {                 // cold generic path
#pragma unroll
                    for (int k = 0; k < 8; ++k) {
                        float a = -__expf(A_log[dd * 16 + g * 8 + k]);
                        e[k] = exp2f(de * a * 1.44269504f);
                    }
                }
                const float4 Bq0 = *(const float4*)&BC[l * 32 + g * 8];
                const float4 Bq1 = *(const float4*)&BC[l * 32 + g * 8 + 4];
                const float4 Cq0 = *(const float4*)&BC[l * 32 + 16 + g * 8];
                const float4 Cq1 = *(const float4*)&BC[l * 32 + 16 + g * 8 + 4];
                const float Bv[8] = {Bq0.x, Bq0.y, Bq0.z, Bq0.w, Bq1.x, Bq1.y, Bq1.z, Bq1.w};
                const float Cv[8] = {Cq0.x, Cq0.y, Cq0.z, Cq0.w, Cq1.x, Cq1.y, Cq1.z, Cq1.w};
                float yp = 0.f;
#pragma unroll
                for (int k = 0; k < 8; ++k) {
                    h[k] = fmaf(e[k], h[k], du * Bv[k]);
                    yp = fmaf(h[k], Cv[k], yp);
                    P[k] *= e[k];
                    K[k] = fmaf(zs * Cv[k], P[k], K[k]);
                }
                const float y = yp + __shfl_xor(yp, 1);
                const float g_l = fmaf(xc, dskip, y) * zs;
                gsum += g_l;
                if (last_tile && l == TILE - 1 && sidx == nseg - 1) {
#pragma unroll
                    for (int k = 0; k < 8; ++k) czs[k] = zs * Cv[k];
                    sl = zs * xc * dskip;
                }
            }
        }
        __syncthreads();
    }

    // ---- segment summary writeout ----
    {
        const size_t sb = (size_t)sidx * Bn + b;
#pragma unroll
        for (int k = 0; k < 8; ++k) {
            const size_t o = (sb * 16 + g * 8 + k) * 128 + dd;
            Qg[o] = h[k];
            Pg[o] = P[k];
            Kg[o] = K[k];
        }
        if (g == 0) GS[sb * 128 + dd] = gsum;
        if (sidx == nseg - 1) {
#pragma unroll
            for (int k = 0; k < 8; ++k)
                CZ[((size_t)b * 16 + g * 8 + k) * 128 + dd] = czs[k];
            if (g == 0) SL[(size_t)b * 128 + dd] = sl;
        }
    }
}

// ---- stitch: chain segment summaries, out_proj, fused keys ----
__global__ __launch_bounds__(128)
void stitch(const float* __restrict__ Qg, const float* __restrict__ Pg,
            const float* __restrict__ Kg, const float* __restrict__ GS,
            const float* __restrict__ CZ, const float* __restrict__ SL,
            const float* __restrict__ out_proj_w,
            const float* __restrict__ k_w, const float* __restrict__ k_b,
            float* __restrict__ pooled, float* __restrict__ keysT,
            int Bn, int seg_shift)
{
    const int nseg = 1 << seg_shift;
    const int b = blockIdx.x, d = threadIdx.x;
    __shared__ float gb[256];
    __shared__ float pl[128];

    float h[16];
#pragma unroll
    for (int n = 0; n < 16; ++n) h[n] = 0.f;
    float gsum = 0.f;
    for (int s = 0; s < nseg; ++s) {
        const size_t sb = (size_t)s * Bn + b;
        gsum += GS[sb * 128 + d];
        float corr = 0.f;
#pragma unroll
        for (int n = 0; n < 16; ++n) {
            const size_t o = (sb * 16 + n) * 128 + d;
            corr = fmaf(Kg[o], h[n], corr);        // uses pre-update h
            h[n] = fmaf(Pg[o], h[n], Qg[o]);
        }
        gsum += corr;
    }
    float glast = SL[(size_t)b * 128 + d];
#pragma unroll
    for (int n = 0; n < 16; ++n)
        glast = fmaf(CZ[((size_t)b * 16 + n) * 128 + d], h[n], glast);

    gb[d] = gsum * (1.f / (float)L_SEQ);
    gb[128 + d] = glast;
    __syncthreads();
    {
        const int half = d >> 6, oc = d & 63;
        const float* gbp = &gb[half * 128];
        float s = 0.f;
#pragma unroll 16
        for (int i = 0; i < 128; ++i) s = fmaf(gbp[i], out_proj_w[i * 64 + oc], s);
        pooled[(size_t)b * 128 + d] = s;
        pl[d] = s;
    }
    __syncthreads();
    if (d < 64) {
        float s = k_b[d];
#pragma unroll 16
        for (int i = 0; i < 128; ++i) s = fmaf(pl[i], k_w[i * 64 + d], s);
        keysT[(size_t)d * Bn + b] = s;
    }
}

// ---- qk: per query row, q = pooled[idx] @ q_w + q_b ; out = q @ keysT ----
__global__ __launch_bounds__(256)
void qk_kernel(const float* __restrict__ pooled, const int* __restrict__ idx,
               const float* __restrict__ q_w, const float* __restrict__ q_b,
               const float* __restrict__ keysT, float* __restrict__ out, int B)
{
    int n = blockIdx.x, t = threadIdx.x;
    __shared__ float p_lds[128];
    __shared__ float q_lds[64];
    int bi = idx[n];
    if (t < 128) p_lds[t] = pooled[(size_t)bi * 128 + t];
    __syncthreads();
    if (t < 64) {
        float s = q_b[t];
#pragma unroll
        for (int i = 0; i < 128; ++i) s = fmaf(p_lds[i], q_w[i * 64 + t], s);
        q_lds[t] = s;
    }
    __syncthreads();
    for (int m = t; m < B; m += 256) {
        float acc = 0.f;
#pragma unroll
        for (int i = 0; i < 64; ++i) acc = fmaf(q_lds[i], keysT[(size_t)i * B + m], acc);
        out[(size_t)n * B + m] = acc;
    }
}

// ============================ LAUNCH ============================

extern "C" void kernel_launch(void* const* d_in, const int* in_sizes, int n_in,
                              void* d_out, int out_size, void* d_ws, size_t ws_size,
                              hipStream_t stream)
{
    const float* reads      = (const float*)d_in[0];
    const int*   idx        = (const int*)d_in[1];
    const float* exp_w      = (const float*)d_in[2];
    const float* exp_b      = (const float*)d_in[3];
    const float* in_proj_w  = (const float*)d_in[4];
    const float* conv_w     = (const float*)d_in[5];
    const float* conv_b     = (const float*)d_in[6];
    const float* x_proj_w   = (const float*)d_in[7];
    const float* dt_w       = (const float*)d_in[8];
    const float* dt_b       = (const float*)d_in[9];
    const float* A_log      = (const float*)d_in[10];
    const float* D_skip     = (const float*)d_in[11];
    const float* out_proj_w = (const float*)d_in[12];
    const float* q_w        = (const float*)d_in[13];
    const float* q_b        = (const float*)d_in[14];
    const float* k_w        = (const float*)d_in[15];
    const float* k_b        = (const float*)d_in[16];

    const int B = in_sizes[0] / (L_SEQ * 4);
    const int N = in_sizes[1];

    char* wsb = (char*)d_ws;
    size_t off = 0;
    auto alloc = [&](size_t bytes) {
        size_t o = off;
        off = (off + bytes + 255) & ~(size_t)255;
        return o;
    };

    float* pooled = (float*)(wsb + alloc((size_t)B * 128 * 4));
    float* keysT  = (float*)(wsb + alloc((size_t)B * 64 * 4));
    float* weff   = (float*)(wsb + alloc(1024 * 4));
    float* beff   = (float*)(wsb + alloc(256 * 4));
    float* xpwt   = (float*)(wsb + alloc(36 * 132 * 4));

    // summary sizes for a given seg_shift (all f32)
    auto summ_bytes = [&](int shift) {
        size_t rows = ((size_t)B << shift) * 16 * 128;
        return rows * 4 * 3                       // Qg, Pg, Kg
             + ((size_t)B << shift) * 128 * 4     // GS
             + (size_t)B * 16 * 128 * 4           // CZ
             + (size_t)B * 128 * 4 + 4096;        // SL + align slack
    };
    int seg_shift = 2;
    if (off + summ_bytes(2) > ws_size) seg_shift = 0;   // fallback: unsegmented

    const int nseg = 1 << seg_shift;
    const size_t rows = (size_t)B * nseg * 16 * 128;
    float* Qg = (float*)(wsb + alloc(rows * 4));
    float* Pg = (float*)(wsb + alloc(rows * 4));
    float* Kg = (float*)(wsb + alloc(rows * 4));
    float* GS = (float*)(wsb + alloc((size_t)B * nseg * 128 * 4));
    float* CZ = (float*)(wsb + alloc((size_t)B * 16 * 128 * 4));
    float* SL = (float*)(wsb + alloc((size_t)B * 128 * 4));

    k_prep<<<1, 256, 0, stream>>>(exp_w, exp_b, in_proj_w, x_proj_w, weff, beff, xpwt);
    mamba_seg<<<B * nseg, 256, 0, stream>>>(reads, weff, beff, xpwt, conv_w, conv_b,
                                            dt_w, dt_b, A_log, D_skip,
                                            Qg, Pg, Kg, GS, CZ, SL, B, seg_shift);
    stitch<<<B, 128, 0, stream>>>(Qg, Pg, Kg, GS, CZ, SL, out_proj_w, k_w, k_b,
                                  pooled, keysT, B, seg_shift);
    qk_kernel<<<N, 256, 0, stream>>>(pooled, idx, q_w, q_b, keysT, (float*)d_out, B);
}